// Round 4
// baseline (20999.054 us; speedup 1.0000x reference)
//
#include <hip/hip_runtime.h>
#include <hip/hip_bf16.h>

// TrajectoryDecoder persistent kernel. L=3 GRU (H=512), T=64, B=2048.
// Round 4: PLAIN launch (cooperative API failed in R3), NWG=256 = 1 block/CU
// (co-residency by construction), custom 8-leaf tree grid barrier.
// 6 phases/step:
//   Pa: gi1(192) || gh0a(64)     Pb: gh0b(64x2) || EW1(192)
//   Pc: gi2(192) || gh1a(64)     Pd: gh1b(64x2) || EW2(192)
//   Pe: MLP1(64) || gh2(192)     Pf: MLP2+pos+traj fused with EW0(t+1)
// pos lives in per-WG LDS (WG owns rows 8*wg..8*wg+7 for all t).
// GEMM: 128x128 tile, BK=32, double-buffered LDS, reg prefetch, 4 waves.

#define H 512
#define T_STEPS 64
#define BATCH 2048
#define H3 1536
#define D_IN 256
#define NWG 256
#define NLEAF 8
#define WGS_PER_LEAF (NWG / NLEAF)

typedef __bf16 bf16x8 __attribute__((ext_vector_type(8)));
typedef float f32x4 __attribute__((ext_vector_type(4)));
typedef unsigned short ushort8v __attribute__((ext_vector_type(8)));

__device__ inline unsigned short f2bf(float f) {
    union { float f; unsigned int u; } v{f};
    unsigned int r = v.u + 0x7fffu + ((v.u >> 16) & 1u);
    return (unsigned short)(r >> 16);
}
__device__ inline float sigmoidf_(float x) { return 1.f / (1.f + expf(-x)); }

struct Params {
    const float *z, *cond, *hp_W, *hp_b, *W_ih0, *W_ihr, *W_hh, *b_ih, *b_hh,
                *W1, *b1, *W2, *b2;
    float* out;
    unsigned* bar;
    unsigned short* comb_bf;
    float* h;               // [2048][1536] fp32 carry
    unsigned short* h_bf;   // bf16 shadow
    float *gh0, *gh1, *gh2, *gi, *hid;
    unsigned short *hpW_bf, *Whh_bf, *Wihr_bf, *W1T_bf;
};

// ---- grid barrier: 8-leaf tree, monotonic epochs ----
__device__ inline void gsync(unsigned* bar, unsigned ph, int wg) {
    __syncthreads();
    if (threadIdx.x == 0) {
        __threadfence();
        unsigned* leaf = bar + (wg & (NLEAF - 1)) * 16;
        unsigned old = __hip_atomic_fetch_add(leaf, 1u, __ATOMIC_ACQ_REL,
                                              __HIP_MEMORY_SCOPE_AGENT);
        if ((old + 1u) == ph * WGS_PER_LEAF) {
            unsigned rold = __hip_atomic_fetch_add(bar + NLEAF * 16, 1u,
                                                   __ATOMIC_ACQ_REL,
                                                   __HIP_MEMORY_SCOPE_AGENT);
            if ((rold + 1u) == ph * NLEAF)
                __hip_atomic_store(bar + NLEAF * 16 + 16, ph, __ATOMIC_RELEASE,
                                   __HIP_MEMORY_SCOPE_AGENT);
        }
        while (__hip_atomic_load(bar + NLEAF * 16 + 16, __ATOMIC_ACQUIRE,
                                 __HIP_MEMORY_SCOPE_AGENT) < ph)
            __builtin_amdgcn_s_sleep(1);
    }
    __syncthreads();
}

// ---- one 128x128 tile, C = A(bf16) @ W(bf16)^T, double-buffered LDS ----
__device__ void gemm_tile(const unsigned short* Abf, int lda,
                          const unsigned short* W, float* C, int ldc, int K,
                          const float* bias, bool relu, unsigned short* Cbf,
                          int brow, int bcol, unsigned short (*As)[5120],
                          unsigned short (*Ws)[5120]) {
    const int tid = threadIdx.x;
    const int lane = tid & 63, wid = tid >> 6;
    const int wr = wid >> 1, wc = wid & 1;
    const int r16 = lane & 15, ko = lane >> 4;
    const int sr = tid >> 1, sh = (tid & 1) * 16;
    const int sbase = sr * 40 + sh;

    f32x4 acc[4][4];
#pragma unroll
    for (int i = 0; i < 4; ++i)
#pragma unroll
        for (int j = 0; j < 4; ++j) acc[i][j] = (f32x4)0.f;

    int aoff[4], boff[4];
#pragma unroll
    for (int i = 0; i < 4; ++i) {
        aoff[i] = (wr * 64 + i * 16 + r16) * 40 + ko * 8;
        boff[i] = (wc * 64 + i * 16 + r16) * 40 + ko * 8;
    }

    const unsigned short* arow = Abf + (size_t)(brow + sr) * lda;
    const unsigned short* wrow = W + (size_t)(bcol + sr) * K;
    // preload k0 = 0
    *(ushort8v*)&As[0][sbase] = *(const ushort8v*)(arow + sh);
    *(ushort8v*)&As[0][sbase + 8] = *(const ushort8v*)(arow + sh + 8);
    *(ushort8v*)&Ws[0][sbase] = *(const ushort8v*)(wrow + sh);
    *(ushort8v*)&Ws[0][sbase + 8] = *(const ushort8v*)(wrow + sh + 8);
    __syncthreads();
    int cur = 0;
    for (int k0 = 0; k0 < K; k0 += 32) {
        const bool more = (k0 + 32) < K;
        ushort8v na0, na1, nw0, nw1;
        if (more) {
            na0 = *(const ushort8v*)(arow + k0 + 32 + sh);
            na1 = *(const ushort8v*)(arow + k0 + 32 + sh + 8);
            nw0 = *(const ushort8v*)(wrow + k0 + 32 + sh);
            nw1 = *(const ushort8v*)(wrow + k0 + 32 + sh + 8);
        }
        bf16x8 a[4], b[4];
#pragma unroll
        for (int i = 0; i < 4; ++i) a[i] = *(const bf16x8*)&As[cur][aoff[i]];
#pragma unroll
        for (int i = 0; i < 4; ++i) b[i] = *(const bf16x8*)&Ws[cur][boff[i]];
#pragma unroll
        for (int mi = 0; mi < 4; ++mi)
#pragma unroll
            for (int ni = 0; ni < 4; ++ni)
                acc[mi][ni] = __builtin_amdgcn_mfma_f32_16x16x32_bf16(
                    a[mi], b[ni], acc[mi][ni], 0, 0, 0);
        if (more) {
            *(ushort8v*)&As[cur ^ 1][sbase] = na0;
            *(ushort8v*)&As[cur ^ 1][sbase + 8] = na1;
            *(ushort8v*)&Ws[cur ^ 1][sbase] = nw0;
            *(ushort8v*)&Ws[cur ^ 1][sbase + 8] = nw1;
            __syncthreads();
            cur ^= 1;
        }
    }

    const int crow0 = brow + wr * 64 + (lane >> 4) * 4;
    const int ccol0 = bcol + wc * 64 + r16;
#pragma unroll
    for (int mi = 0; mi < 4; ++mi) {
#pragma unroll
        for (int ni = 0; ni < 4; ++ni) {
            int col = ccol0 + ni * 16;
            float bv = bias ? bias[col] : 0.f;
#pragma unroll
            for (int j = 0; j < 4; ++j) {
                int row = crow0 + mi * 16 + j;
                float v = acc[mi][ni][j] + bv;
                if (relu) v = fmaxf(v, 0.f);
                C[(size_t)row * ldc + col] = v;
                if (Cbf) Cbf[(size_t)row * ldc + col] = f2bf(v);
            }
        }
    }
    __syncthreads();  // LDS safe for next call
}

// ---- EW0 over this WG's 8 rows, pos from LDS ----
__device__ void ew0_rows(const Params& p, int wg, float (*posS)[2]) {
    for (int idx = threadIdx.x; idx < 8 * H; idx += 256) {
        int lrow = idx >> 9, j = idx & 511;
        int b = wg * 8 + lrow;
        float px = posS[lrow][0], py = posS[lrow][1];
        float gi_r = px * p.W_ih0[j * 2 + 0] + py * p.W_ih0[j * 2 + 1] + p.b_ih[j];
        float gi_z = px * p.W_ih0[(512 + j) * 2 + 0] + py * p.W_ih0[(512 + j) * 2 + 1] +
                     p.b_ih[512 + j];
        float gi_n = px * p.W_ih0[(1024 + j) * 2 + 0] + py * p.W_ih0[(1024 + j) * 2 + 1] +
                     p.b_ih[1024 + j];
        size_t rb = (size_t)b * H3;
        float hr = p.gh0[rb + j] + p.b_hh[j];
        float hz = p.gh0[rb + 512 + j] + p.b_hh[512 + j];
        float hn = p.gh0[rb + 1024 + j] + p.b_hh[1024 + j];
        float r = sigmoidf_(gi_r + hr);
        float zg = sigmoidf_(gi_z + hz);
        float n = tanhf(gi_n + r * hn);
        float hv = (1.f - zg) * n + zg * p.h[rb + j];
        p.h[rb + j] = hv;
        p.h_bf[rb + j] = f2bf(hv);
    }
}

// ---- EW for layers 1,2 on WGs [wgbase, wgbase+nwgs) ----
__device__ void ewl(const Params& p, const float* gh, int l, int wgbase, int nwgs,
                    int wg) {
    const float* b_ihl = p.b_ih + l * H3;
    const float* b_hhl = p.b_hh + l * H3;
    int colOff = l * H;
    for (int idx = (wg - wgbase) * 256 + threadIdx.x; idx < BATCH * H;
         idx += nwgs * 256) {
        int b = idx >> 9, j = idx & 511;
        size_t rb = (size_t)b * H3;
        float ir = p.gi[rb + j] + b_ihl[j];
        float iz = p.gi[rb + 512 + j] + b_ihl[512 + j];
        float inn = p.gi[rb + 1024 + j] + b_ihl[1024 + j];
        float hr = gh[rb + j] + b_hhl[j];
        float hz = gh[rb + 512 + j] + b_hhl[512 + j];
        float hn = gh[rb + 1024 + j] + b_hhl[1024 + j];
        float r = sigmoidf_(ir + hr);
        float zg = sigmoidf_(iz + hz);
        float n = tanhf(inn + r * hn);
        float hv = (1.f - zg) * n + zg * p.h[rb + colOff + j];
        p.h[rb + colOff + j] = hv;
        p.h_bf[rb + colOff + j] = f2bf(hv);
    }
}

// ---- MLP2 + pos(LDS) + traj write, then EW0(t+1) ----
__device__ void step_tail(const Params& p, int t, int wg, float (*posS)[2]) {
    const int tid = threadIdx.x;
    const int lane = tid & 63, wv = tid >> 6;
    const float* W2t = p.W2 + (size_t)t * H * 2;
#pragma unroll
    for (int r = 0; r < 2; ++r) {
        int lrow = wv * 2 + r;
        int row = wg * 8 + lrow;
        const float* hr = p.hid + (size_t)row * H;
        float a0 = 0.f, a1 = 0.f;
        for (int k = lane; k < H; k += 64) {
            float x = hr[k];
            a0 += x * W2t[k * 2 + 0];
            a1 += x * W2t[k * 2 + 1];
        }
#pragma unroll
        for (int off = 32; off; off >>= 1) {
            a0 += __shfl_down(a0, off);
            a1 += __shfl_down(a1, off);
        }
        if (lane == 0) {
            float p0 = posS[lrow][0] + a0 + p.b2[t * 2 + 0];
            float p1 = posS[lrow][1] + a1 + p.b2[t * 2 + 1];
            posS[lrow][0] = p0;
            posS[lrow][1] = p1;
            p.out[((size_t)row * T_STEPS + t) * 2 + 0] = p0;
            p.out[((size_t)row * T_STEPS + t) * 2 + 1] = p1;
        }
    }
    if (t + 1 < T_STEPS) {
        __syncthreads();   // posS visible to all threads
        ew0_rows(p, wg, posS);
    }
}

__device__ void convert_range(const float* in, unsigned short* out, int n, int wg) {
    for (size_t i = ((size_t)wg * 256 + threadIdx.x) * 8; i < (size_t)n;
         i += (size_t)NWG * 256 * 8) {
        float4 v0 = *(const float4*)(in + i);
        float4 v1 = *(const float4*)(in + i + 4);
        ushort8v q;
        q[0] = f2bf(v0.x); q[1] = f2bf(v0.y); q[2] = f2bf(v0.z); q[3] = f2bf(v0.w);
        q[4] = f2bf(v1.x); q[5] = f2bf(v1.y); q[6] = f2bf(v1.z); q[7] = f2bf(v1.w);
        *(ushort8v*)(out + i) = q;
    }
}

__global__ __launch_bounds__(256) void persist(Params p) {
    const int wg = blockIdx.x;
    __shared__ unsigned short As[2][5120];
    __shared__ unsigned short Ws[2][5120];
    __shared__ float ttile[32][33];
    __shared__ float posS[8][2];
    unsigned ph = 0;

    if (threadIdx.x < 16) posS[threadIdx.x >> 1][threadIdx.x & 1] = 0.f;

    // ---- Ph0: combined(bf16) + weight converts + W1 transpose ----
    for (int idx = wg * 256 + threadIdx.x; idx < BATCH * D_IN; idx += NWG * 256) {
        int b = idx >> 8, k = idx & 255;
        float v = (k < 128) ? p.z[b * 128 + k] : p.cond[b * 128 + (k - 128)];
        p.comb_bf[idx] = f2bf(v);
    }
    convert_range(p.hp_W, p.hpW_bf, H3 * D_IN, wg);
    convert_range(p.W_hh, p.Whh_bf, 3 * H3 * H, wg);
    convert_range(p.W_ihr, p.Wihr_bf, 2 * H3 * H, wg);
    {
        int tx = threadIdx.x & 31, ty = threadIdx.x >> 5;
        for (int tile = wg; tile < T_STEPS * 16 * 16; tile += NWG) {
            int t_ = tile >> 8, rem = tile & 255;
            int n0 = (rem & 15) * 32, k0c = (rem >> 4) * 32;
            __syncthreads();
#pragma unroll
            for (int j = 0; j < 4; ++j)
                ttile[ty + 8 * j][tx] =
                    p.W1[((size_t)t_ * 512 + k0c + ty + 8 * j) * 512 + n0 + tx];
            __syncthreads();
#pragma unroll
            for (int j = 0; j < 4; ++j)
                p.W1T_bf[((size_t)t_ * 512 + n0 + ty + 8 * j) * 512 + k0c + tx] =
                    f2bf(ttile[tx][ty + 8 * j]);
        }
    }
    gsync(p.bar, ++ph, wg);

    // ---- Ph1: h_init = combined @ hp_W^T + hp_b ----
    if (wg < 192)
        gemm_tile(p.comb_bf, D_IN, p.hpW_bf, p.h, H3, D_IN, p.hp_b, false, p.h_bf,
                  (wg / 12) * 128, (wg % 12) * 128, As, Ws);
    gsync(p.bar, ++ph, wg);

    // ---- Ph2: gh0(0), gh1(0), gh2(0) : 576 tiles ----
    for (int tile = wg; tile < 576; tile += NWG) {
        int g = tile / 192, r = tile % 192;
        float* C = (g == 0) ? p.gh0 : (g == 1 ? p.gh1 : p.gh2);
        gemm_tile(p.h_bf + g * H, H3, p.Whh_bf + (size_t)g * H3 * H, C, H3, H,
                  nullptr, false, nullptr, (r / 12) * 128, (r % 12) * 128, As, Ws);
    }
    gsync(p.bar, ++ph, wg);

    // ---- Ph3: EW0(t=0) ----
    ew0_rows(p, wg, posS);
    gsync(p.bar, ++ph, wg);

    for (int t = 0; t < T_STEPS; ++t) {
        // Pa: gi1 = h0(t) @ W_ihr[0]^T (192) || gh0(t+1) tiles 0..63
        if (wg < 192) {
            gemm_tile(p.h_bf, H3, p.Wihr_bf, p.gi, H3, H, nullptr, false, nullptr,
                      (wg / 12) * 128, (wg % 12) * 128, As, Ws);
        } else if (t + 1 < T_STEPS) {
            int g = wg - 192;
            gemm_tile(p.h_bf, H3, p.Whh_bf, p.gh0, H3, H, nullptr, false, nullptr,
                      (g / 12) * 128, (g % 12) * 128, As, Ws);
        }
        gsync(p.bar, ++ph, wg);
        // Pb: gh0(t+1) tiles 64..191 (64 WG x2) || EW1 (192 WG)
        if (wg < 64) {
            if (t + 1 < T_STEPS)
                for (int g = 64 + wg; g < 192; g += 64)
                    gemm_tile(p.h_bf, H3, p.Whh_bf, p.gh0, H3, H, nullptr, false,
                              nullptr, (g / 12) * 128, (g % 12) * 128, As, Ws);
        } else {
            ewl(p, p.gh1, 1, 64, 192, wg);
        }
        gsync(p.bar, ++ph, wg);
        // Pc: gi2 = h1(t) @ W_ihr[1]^T (192) || gh1(t+1) tiles 0..63
        if (wg < 192) {
            gemm_tile(p.h_bf + H, H3, p.Wihr_bf + (size_t)H3 * H, p.gi, H3, H,
                      nullptr, false, nullptr, (wg / 12) * 128, (wg % 12) * 128,
                      As, Ws);
        } else if (t + 1 < T_STEPS) {
            int g = wg - 192;
            gemm_tile(p.h_bf + H, H3, p.Whh_bf + (size_t)H3 * H, p.gh1, H3, H,
                      nullptr, false, nullptr, (g / 12) * 128, (g % 12) * 128,
                      As, Ws);
        }
        gsync(p.bar, ++ph, wg);
        // Pd: gh1(t+1) tiles 64..191 || EW2 (192 WG)
        if (wg < 64) {
            if (t + 1 < T_STEPS)
                for (int g = 64 + wg; g < 192; g += 64)
                    gemm_tile(p.h_bf + H, H3, p.Whh_bf + (size_t)H3 * H, p.gh1, H3,
                              H, nullptr, false, nullptr, (g / 12) * 128,
                              (g % 12) * 128, As, Ws);
        } else {
            ewl(p, p.gh2, 2, 64, 192, wg);
        }
        gsync(p.bar, ++ph, wg);
        // Pe: MLP1 (64) || gh2(t+1) (192)
        if (wg < 64) {
            gemm_tile(p.h_bf + 2 * H, H3, p.W1T_bf + (size_t)t * H * H, p.hid, H,
                      H, p.b1 + (size_t)t * H, true, nullptr, (wg >> 2) * 128,
                      (wg & 3) * 128, As, Ws);
        } else if (t + 1 < T_STEPS) {
            int g = wg - 64;
            gemm_tile(p.h_bf + 2 * H, H3, p.Whh_bf + (size_t)2 * H3 * H, p.gh2, H3,
                      H, nullptr, false, nullptr, (g / 12) * 128, (g % 12) * 128,
                      As, Ws);
        }
        gsync(p.bar, ++ph, wg);
        // Pf: MLP2 + pos + traj + EW0(t+1)
        step_tail(p, t, wg, posS);
        gsync(p.bar, ++ph, wg);
    }
}

extern "C" void kernel_launch(void* const* d_in, const int* in_sizes, int n_in,
                              void* d_out, int out_size, void* d_ws, size_t ws_size,
                              hipStream_t stream) {
    Params p;
    p.z = (const float*)d_in[0];
    p.cond = (const float*)d_in[1];
    p.hp_W = (const float*)d_in[2];
    p.hp_b = (const float*)d_in[3];
    p.W_ih0 = (const float*)d_in[4];
    p.W_ihr = (const float*)d_in[5];
    p.W_hh = (const float*)d_in[6];
    p.b_ih = (const float*)d_in[7];
    p.b_hh = (const float*)d_in[8];
    p.W1 = (const float*)d_in[9];
    p.b1 = (const float*)d_in[10];
    p.W2 = (const float*)d_in[11];
    p.b2 = (const float*)d_in[12];
    p.out = (float*)d_out;

    char* w = (char*)d_ws;
    p.bar = (unsigned*)w;            w += 1024;
    p.comb_bf = (unsigned short*)w;  w += (size_t)BATCH * D_IN * 2;
    p.h = (float*)w;                 w += (size_t)BATCH * H3 * 4;
    p.h_bf = (unsigned short*)w;     w += (size_t)BATCH * H3 * 2;
    p.gh0 = (float*)w;               w += (size_t)BATCH * H3 * 4;
    p.gh1 = (float*)w;               w += (size_t)BATCH * H3 * 4;
    p.gh2 = (float*)w;               w += (size_t)BATCH * H3 * 4;
    p.gi = (float*)w;                w += (size_t)BATCH * H3 * 4;
    p.hid = (float*)w;               w += (size_t)BATCH * H * 4;
    p.hpW_bf = (unsigned short*)w;   w += (size_t)H3 * D_IN * 2;
    p.Whh_bf = (unsigned short*)w;   w += (size_t)3 * H3 * H * 2;
    p.Wihr_bf = (unsigned short*)w;  w += (size_t)2 * H3 * H * 2;
    p.W1T_bf = (unsigned short*)w;   w += (size_t)T_STEPS * H * H * 2;

    hipMemsetAsync(p.bar, 0, 1024, stream);
    persist<<<dim3(NWG), dim3(256), 0, stream>>>(p);
}

// Round 5
// 4851.382 us; speedup vs baseline: 4.3285x; 4.3285x over previous
//
#include <hip/hip_runtime.h>
#include <hip/hip_bf16.h>

// TrajectoryDecoder, multi-kernel (R2 structure rebalanced). L=3 GRU, H=512,
// T=64, B=2048. Per step (7 launches):
//   EW0(+pos finalize of t-1, writes out[t-1])
//   K1: z-batched { gi1(t), gh0(t+1) }  (A = h0(t) shared)     384 blocks
//   EW1
//   K2: z-batched { gi2(t), gh1(t+1) }  (A = h1(t) shared)     384 blocks
//   EW2
//   K3: { MLP1(t)+MLP2-partials epilogue, gh2(t+1) } (A=h2(t)) 256 blocks
// pos finalize: partials[8][B][2] from K3, summed in next EW0 / pos_final.

#define H 512
#define T_STEPS 64
#define BATCH 2048
#define H3 1536
#define D_IN 256

typedef __bf16 bf16x8 __attribute__((ext_vector_type(8)));
typedef float f32x4 __attribute__((ext_vector_type(4)));
typedef unsigned short ushort8v __attribute__((ext_vector_type(8)));
typedef unsigned short ushort4v __attribute__((ext_vector_type(4)));

__device__ inline unsigned short f2bf(float f) {
    union { float f; unsigned int u; } v{f};
    unsigned int r = v.u + 0x7fffu + ((v.u >> 16) & 1u);
    return (unsigned short)(r >> 16);
}
__device__ inline float sigmoidf_(float x) { return 1.f / (1.f + expf(-x)); }

// ---- 128x128 GEMM core: acc = A(bf16,[M][lda]) @ W(bf16,[N][K])^T ----
__device__ inline void gemm_core(const unsigned short* Abf, int lda,
                                 const unsigned short* W, int K, int brow,
                                 int bcol, unsigned short* As, unsigned short* Ws,
                                 f32x4 (&acc)[4][4]) {
    const int tid = threadIdx.x;
    const int lane = tid & 63, wid = tid >> 6;
    const int wr = wid >> 1, wc = wid & 1;
    const int r16 = lane & 15, ko = lane >> 4;
    const int sr = tid >> 1, sh = (tid & 1) * 16;
#pragma unroll
    for (int i = 0; i < 4; ++i)
#pragma unroll
        for (int j = 0; j < 4; ++j) acc[i][j] = (f32x4)0.f;
    int aoff[4], boff[4];
#pragma unroll
    for (int i = 0; i < 4; ++i) {
        aoff[i] = (wr * 64 + i * 16 + r16) * 40 + ko * 8;
        boff[i] = (wc * 64 + i * 16 + r16) * 40 + ko * 8;
    }
    const unsigned short* arow = Abf + (size_t)(brow + sr) * lda;
    const unsigned short* wrow = W + (size_t)(bcol + sr) * K;
    for (int k0 = 0; k0 < K; k0 += 32) {
        *(ushort8v*)&As[sr * 40 + sh] = *(const ushort8v*)(arow + k0 + sh);
        *(ushort8v*)&As[sr * 40 + sh + 8] = *(const ushort8v*)(arow + k0 + sh + 8);
        *(ushort8v*)&Ws[sr * 40 + sh] = *(const ushort8v*)(wrow + k0 + sh);
        *(ushort8v*)&Ws[sr * 40 + sh + 8] = *(const ushort8v*)(wrow + k0 + sh + 8);
        __syncthreads();
        bf16x8 a[4], b[4];
#pragma unroll
        for (int i = 0; i < 4; ++i) a[i] = *(const bf16x8*)&As[aoff[i]];
#pragma unroll
        for (int i = 0; i < 4; ++i) b[i] = *(const bf16x8*)&Ws[boff[i]];
#pragma unroll
        for (int mi = 0; mi < 4; ++mi)
#pragma unroll
            for (int ni = 0; ni < 4; ++ni)
                acc[mi][ni] = __builtin_amdgcn_mfma_f32_16x16x32_bf16(
                    a[mi], b[ni], acc[mi][ni], 0, 0, 0);
        __syncthreads();
    }
}

__device__ inline void epilogue_store(f32x4 (&acc)[4][4], float* C, int ldc,
                                      const float* bias, bool relu,
                                      unsigned short* Cbf, int brow, int bcol) {
    const int lane = threadIdx.x & 63, wid = threadIdx.x >> 6;
    const int wr = wid >> 1, wc = wid & 1, r16 = lane & 15;
    const int crow0 = brow + wr * 64 + (lane >> 4) * 4;
    const int ccol0 = bcol + wc * 64 + r16;
#pragma unroll
    for (int mi = 0; mi < 4; ++mi)
#pragma unroll
        for (int ni = 0; ni < 4; ++ni) {
            int col = ccol0 + ni * 16;
            float bv = bias ? bias[col] : 0.f;
#pragma unroll
            for (int j = 0; j < 4; ++j) {
                int row = crow0 + mi * 16 + j;
                float v = acc[mi][ni][j] + bv;
                if (relu) v = fmaxf(v, 0.f);
                C[(size_t)row * ldc + col] = v;
                if (Cbf) Cbf[(size_t)row * ldc + col] = f2bf(v);
            }
        }
}

// MLP: hid = relu(acc + b1); partial[strip][row][2] = hid-block @ W2-slice
__device__ inline void epilogue_mlp(f32x4 (&acc)[4][4], const float* b1t,
                                    const float* W2t, float* partials, int brow,
                                    int bcol) {
    const int lane = threadIdx.x & 63, wid = threadIdx.x >> 6;
    const int wr = wid >> 1, wc = wid & 1, r16 = lane & 15;
    const int crow0 = brow + wr * 64 + (lane >> 4) * 4;
    const int ccol0 = bcol + wc * 64 + r16;
    const int strip = (bcol >> 7) * 2 + wc;
    float d0[4][4], d1[4][4];
#pragma unroll
    for (int mi = 0; mi < 4; ++mi)
#pragma unroll
        for (int j = 0; j < 4; ++j) { d0[mi][j] = 0.f; d1[mi][j] = 0.f; }
#pragma unroll
    for (int ni = 0; ni < 4; ++ni) {
        int col = ccol0 + ni * 16;
        float bv = b1t[col];
        float w20 = W2t[col * 2 + 0], w21 = W2t[col * 2 + 1];
#pragma unroll
        for (int mi = 0; mi < 4; ++mi)
#pragma unroll
            for (int j = 0; j < 4; ++j) {
                float hv = fmaxf(acc[mi][ni][j] + bv, 0.f);
                d0[mi][j] += hv * w20;
                d1[mi][j] += hv * w21;
            }
    }
#pragma unroll
    for (int m = 1; m < 16; m <<= 1)
#pragma unroll
        for (int mi = 0; mi < 4; ++mi)
#pragma unroll
            for (int j = 0; j < 4; ++j) {
                d0[mi][j] += __shfl_xor(d0[mi][j], m);
                d1[mi][j] += __shfl_xor(d1[mi][j], m);
            }
    if (r16 == 0) {
#pragma unroll
        for (int mi = 0; mi < 4; ++mi)
#pragma unroll
            for (int j = 0; j < 4; ++j) {
                int row = crow0 + mi * 16 + j;
                float2 v = make_float2(d0[mi][j], d1[mi][j]);
                *(float2*)&partials[((size_t)strip * BATCH + row) * 2] = v;
            }
    }
}

// ---- GEMM kernels ----
__global__ __launch_bounds__(256) void k_init(const unsigned short* comb,
                                              const unsigned short* hpW, float* h,
                                              unsigned short* h_bf,
                                              const float* hp_b) {
    __shared__ unsigned short As[5120], Ws[5120];
    f32x4 acc[4][4];
    int bid = blockIdx.x;  // 192
    gemm_core(comb, D_IN, hpW, D_IN, (bid / 12) * 128, (bid % 12) * 128, As, Ws, acc);
    epilogue_store(acc, h, H3, hp_b, false, h_bf, (bid / 12) * 128, (bid % 12) * 128);
}

__global__ __launch_bounds__(256) void k_gh3(const unsigned short* h_bf,
                                             const unsigned short* Whh, float* gh0,
                                             float* gh1, float* gh2) {
    __shared__ unsigned short As[5120], Ws[5120];
    f32x4 acc[4][4];
    int bid = blockIdx.x;  // 576
    int g = bid / 192, r = bid % 192;
    float* C = (g == 0) ? gh0 : (g == 1 ? gh1 : gh2);
    gemm_core(h_bf + g * H, H3, Whh + (size_t)g * H3 * H, H, (r / 12) * 128,
              (r % 12) * 128, As, Ws, acc);
    epilogue_store(acc, C, H3, nullptr, false, nullptr, (r / 12) * 128,
                   (r % 12) * 128);
}

__global__ __launch_bounds__(256) void k_dual(const unsigned short* A,
                                              const unsigned short* W0, float* C0,
                                              const unsigned short* W1, float* C1,
                                              int skip2) {
    __shared__ unsigned short As[5120], Ws[5120];
    f32x4 acc[4][4];
    int bid = blockIdx.x;  // 384
    int half = bid >= 192;
    if (half && skip2) return;
    int r = bid - half * 192;
    const unsigned short* W = half ? W1 : W0;
    float* C = half ? C1 : C0;
    gemm_core(A, H3, W, H, (r / 12) * 128, (r % 12) * 128, As, Ws, acc);
    epilogue_store(acc, C, H3, nullptr, false, nullptr, (r / 12) * 128,
                   (r % 12) * 128);
}

__global__ __launch_bounds__(256) void k_mlp_gh(const unsigned short* A,
                                                const unsigned short* W1Tt,
                                                const float* b1t, const float* W2t,
                                                float* partials,
                                                const unsigned short* Whh2,
                                                float* gh2, int skip2) {
    __shared__ unsigned short As[5120], Ws[5120];
    f32x4 acc[4][4];
    int bid = blockIdx.x;  // 256 = 64 MLP + 192 gh2
    if (bid < 64) {
        int brow = (bid >> 2) * 128, bcol = (bid & 3) * 128;
        gemm_core(A, H3, W1Tt, H, brow, bcol, As, Ws, acc);
        epilogue_mlp(acc, b1t, W2t, partials, brow, bcol);
    } else {
        if (skip2) return;
        int r = bid - 64;
        gemm_core(A, H3, Whh2, H, (r / 12) * 128, (r % 12) * 128, As, Ws, acc);
        epilogue_store(acc, gh2, H3, nullptr, false, nullptr, (r / 12) * 128,
                       (r % 12) * 128);
    }
}

// ---- EW kernels (1024 blocks, 2 rows/block, float4 per thread) ----
__global__ __launch_bounds__(256) void k_ew0(const float* gh0, float* h,
                                             unsigned short* h_bf,
                                             const float* W_ih0, const float* b_ih,
                                             const float* b_hh, float* pos,
                                             const float* partials, const float* b2,
                                             float* out, int t) {
    __shared__ float posS[2][2];
    const int tid = threadIdx.x, bid = blockIdx.x;
    if (tid < 2) {
        int b = bid * 2 + tid;
        float p0 = pos[b * 2 + 0], p1 = pos[b * 2 + 1];
        if (t > 0) {
            float s0 = 0.f, s1 = 0.f;
#pragma unroll
            for (int s = 0; s < 8; ++s) {
                float2 v = *(const float2*)&partials[((size_t)s * BATCH + b) * 2];
                s0 += v.x; s1 += v.y;
            }
            p0 += s0 + b2[(t - 1) * 2 + 0];
            p1 += s1 + b2[(t - 1) * 2 + 1];
            pos[b * 2 + 0] = p0;
            pos[b * 2 + 1] = p1;
            out[((size_t)b * T_STEPS + (t - 1)) * 2 + 0] = p0;
            out[((size_t)b * T_STEPS + (t - 1)) * 2 + 1] = p1;
        }
        posS[tid][0] = p0;
        posS[tid][1] = p1;
    }
    __syncthreads();
    const int lrow = tid >> 7, j0 = (tid & 127) * 4;
    const int b = bid * 2 + lrow;
    const size_t rb = (size_t)b * H3;
    const float px = posS[lrow][0], py = posS[lrow][1];
    float4 g0 = *(const float4*)&gh0[rb + j0];
    float4 g1 = *(const float4*)&gh0[rb + 512 + j0];
    float4 g2 = *(const float4*)&gh0[rb + 1024 + j0];
    float4 wrA = *(const float4*)&W_ih0[(0 * 512 + j0) * 2];
    float4 wrB = *(const float4*)&W_ih0[(0 * 512 + j0) * 2 + 4];
    float4 wzA = *(const float4*)&W_ih0[(1 * 512 + j0) * 2];
    float4 wzB = *(const float4*)&W_ih0[(1 * 512 + j0) * 2 + 4];
    float4 wnA = *(const float4*)&W_ih0[(2 * 512 + j0) * 2];
    float4 wnB = *(const float4*)&W_ih0[(2 * 512 + j0) * 2 + 4];
    float4 bir = *(const float4*)&b_ih[j0];
    float4 biz = *(const float4*)&b_ih[512 + j0];
    float4 bin = *(const float4*)&b_ih[1024 + j0];
    float4 bhr = *(const float4*)&b_hh[j0];
    float4 bhz = *(const float4*)&b_hh[512 + j0];
    float4 bhn = *(const float4*)&b_hh[1024 + j0];
    float4 h4 = *(const float4*)&h[rb + j0];
    float wr_[8] = {wrA.x, wrA.y, wrA.z, wrA.w, wrB.x, wrB.y, wrB.z, wrB.w};
    float wz_[8] = {wzA.x, wzA.y, wzA.z, wzA.w, wzB.x, wzB.y, wzB.z, wzB.w};
    float wn_[8] = {wnA.x, wnA.y, wnA.z, wnA.w, wnB.x, wnB.y, wnB.z, wnB.w};
    float gr[4] = {g0.x, g0.y, g0.z, g0.w};
    float gz[4] = {g1.x, g1.y, g1.z, g1.w};
    float gn[4] = {g2.x, g2.y, g2.z, g2.w};
    float bi_r[4] = {bir.x, bir.y, bir.z, bir.w};
    float bi_z[4] = {biz.x, biz.y, biz.z, biz.w};
    float bi_n[4] = {bin.x, bin.y, bin.z, bin.w};
    float bh_r[4] = {bhr.x, bhr.y, bhr.z, bhr.w};
    float bh_z[4] = {bhz.x, bhz.y, bhz.z, bhz.w};
    float bh_n[4] = {bhn.x, bhn.y, bhn.z, bhn.w};
    float hv[4] = {h4.x, h4.y, h4.z, h4.w};
    float4 ho;
    ushort4v hbo;
#pragma unroll
    for (int k = 0; k < 4; ++k) {
        float gi_r = px * wr_[k * 2] + py * wr_[k * 2 + 1] + bi_r[k];
        float gi_z = px * wz_[k * 2] + py * wz_[k * 2 + 1] + bi_z[k];
        float gi_n = px * wn_[k * 2] + py * wn_[k * 2 + 1] + bi_n[k];
        float r = sigmoidf_(gi_r + gr[k] + bh_r[k]);
        float zg = sigmoidf_(gi_z + gz[k] + bh_z[k]);
        float n = tanhf(gi_n + r * (gn[k] + bh_n[k]));
        float nh = (1.f - zg) * n + zg * hv[k];
        ((float*)&ho)[k] = nh;
        hbo[k] = f2bf(nh);
    }
    *(float4*)&h[rb + j0] = ho;
    *(ushort4v*)&h_bf[rb + j0] = hbo;
}

__global__ __launch_bounds__(256) void k_ewl(const float* gi, const float* gh,
                                             float* h, unsigned short* h_bf,
                                             const float* b_ihl, const float* b_hhl,
                                             int colOff) {
    const int tid = threadIdx.x, bid = blockIdx.x;
    const int lrow = tid >> 7, j0 = (tid & 127) * 4;
    const int b = bid * 2 + lrow;
    const size_t rb = (size_t)b * H3;
    float4 ir4 = *(const float4*)&gi[rb + j0];
    float4 iz4 = *(const float4*)&gi[rb + 512 + j0];
    float4 in4 = *(const float4*)&gi[rb + 1024 + j0];
    float4 hr4 = *(const float4*)&gh[rb + j0];
    float4 hz4 = *(const float4*)&gh[rb + 512 + j0];
    float4 hn4 = *(const float4*)&gh[rb + 1024 + j0];
    float4 bir = *(const float4*)&b_ihl[j0];
    float4 biz = *(const float4*)&b_ihl[512 + j0];
    float4 bin = *(const float4*)&b_ihl[1024 + j0];
    float4 bhr = *(const float4*)&b_hhl[j0];
    float4 bhz = *(const float4*)&b_hhl[512 + j0];
    float4 bhn = *(const float4*)&b_hhl[1024 + j0];
    float4 h4 = *(const float4*)&h[rb + colOff + j0];
    float irv[4] = {ir4.x, ir4.y, ir4.z, ir4.w};
    float izv[4] = {iz4.x, iz4.y, iz4.z, iz4.w};
    float inv[4] = {in4.x, in4.y, in4.z, in4.w};
    float hrv[4] = {hr4.x, hr4.y, hr4.z, hr4.w};
    float hzv[4] = {hz4.x, hz4.y, hz4.z, hz4.w};
    float hnv[4] = {hn4.x, hn4.y, hn4.z, hn4.w};
    float bi_r[4] = {bir.x, bir.y, bir.z, bir.w};
    float bi_z[4] = {biz.x, biz.y, biz.z, biz.w};
    float bi_n[4] = {bin.x, bin.y, bin.z, bin.w};
    float bh_r[4] = {bhr.x, bhr.y, bhr.z, bhr.w};
    float bh_z[4] = {bhz.x, bhz.y, bhz.z, bhz.w};
    float bh_n[4] = {bhn.x, bhn.y, bhn.z, bhn.w};
    float hv[4] = {h4.x, h4.y, h4.z, h4.w};
    float4 ho;
    ushort4v hbo;
#pragma unroll
    for (int k = 0; k < 4; ++k) {
        float r = sigmoidf_(irv[k] + bi_r[k] + hrv[k] + bh_r[k]);
        float zg = sigmoidf_(izv[k] + bi_z[k] + hzv[k] + bh_z[k]);
        float n = tanhf(inv[k] + bi_n[k] + r * (hnv[k] + bh_n[k]));
        float nh = (1.f - zg) * n + zg * hv[k];
        ((float*)&ho)[k] = nh;
        hbo[k] = f2bf(nh);
    }
    *(float4*)&h[rb + colOff + j0] = ho;
    *(ushort4v*)&h_bf[rb + colOff + j0] = hbo;
}

__global__ __launch_bounds__(256) void k_posfin(const float* partials, float* pos,
                                                const float* b2, float* out) {
    int b = blockIdx.x * 256 + threadIdx.x;
    float s0 = 0.f, s1 = 0.f;
#pragma unroll
    for (int s = 0; s < 8; ++s) {
        float2 v = *(const float2*)&partials[((size_t)s * BATCH + b) * 2];
        s0 += v.x; s1 += v.y;
    }
    float p0 = pos[b * 2 + 0] + s0 + b2[63 * 2 + 0];
    float p1 = pos[b * 2 + 1] + s1 + b2[63 * 2 + 1];
    out[((size_t)b * T_STEPS + 63) * 2 + 0] = p0;
    out[((size_t)b * T_STEPS + 63) * 2 + 1] = p1;
}

// ---- prologue helpers ----
__global__ __launch_bounds__(256) void k_comb(const float* z, const float* cond,
                                              unsigned short* comb, float* pos) {
    int idx = blockIdx.x * 256 + threadIdx.x;
    int b = idx >> 8, k = idx & 255;
    float v = (k < 128) ? z[b * 128 + k] : cond[b * 128 + (k - 128)];
    comb[idx] = f2bf(v);
    if (idx < BATCH * 2) pos[idx] = 0.f;
}

__global__ __launch_bounds__(256) void k_conv(const float* in, unsigned short* out) {
    size_t i = ((size_t)blockIdx.x * 256 + threadIdx.x) * 8;
    float4 v0 = *(const float4*)(in + i);
    float4 v1 = *(const float4*)(in + i + 4);
    ushort8v p;
    p[0] = f2bf(v0.x); p[1] = f2bf(v0.y); p[2] = f2bf(v0.z); p[3] = f2bf(v0.w);
    p[4] = f2bf(v1.x); p[5] = f2bf(v1.y); p[6] = f2bf(v1.z); p[7] = f2bf(v1.w);
    *(ushort8v*)(out + i) = p;
}

__global__ __launch_bounds__(256) void k_trw1(const float* W1, unsigned short* W1T) {
    __shared__ float tile[32][33];
    int t = blockIdx.z;
    int n0 = blockIdx.x * 32, k0 = blockIdx.y * 32;
    int tx = threadIdx.x & 31, ty = threadIdx.x >> 5;
#pragma unroll
    for (int j = 0; j < 4; ++j)
        tile[ty + 8 * j][tx] = W1[((size_t)t * 512 + k0 + ty + 8 * j) * 512 + n0 + tx];
    __syncthreads();
#pragma unroll
    for (int j = 0; j < 4; ++j)
        W1T[((size_t)t * 512 + n0 + ty + 8 * j) * 512 + k0 + tx] =
            f2bf(tile[tx][ty + 8 * j]);
}

extern "C" void kernel_launch(void* const* d_in, const int* in_sizes, int n_in,
                              void* d_out, int out_size, void* d_ws, size_t ws_size,
                              hipStream_t stream) {
    const float* z = (const float*)d_in[0];
    const float* cond = (const float*)d_in[1];
    const float* hp_W = (const float*)d_in[2];
    const float* hp_b = (const float*)d_in[3];
    const float* W_ih0 = (const float*)d_in[4];
    const float* W_ihr = (const float*)d_in[5];
    const float* W_hh = (const float*)d_in[6];
    const float* b_ih = (const float*)d_in[7];
    const float* b_hh = (const float*)d_in[8];
    const float* W1 = (const float*)d_in[9];
    const float* b1 = (const float*)d_in[10];
    const float* W2 = (const float*)d_in[11];
    const float* b2 = (const float*)d_in[12];
    float* out = (float*)d_out;

    char* w = (char*)d_ws;
    float* pos = (float*)w;           w += (size_t)BATCH * 2 * 4;
    float* partials = (float*)w;      w += (size_t)8 * BATCH * 2 * 4;
    float* h = (float*)w;             w += (size_t)BATCH * H3 * 4;
    float* gi = (float*)w;            w += (size_t)BATCH * H3 * 4;
    float* gh0 = (float*)w;           w += (size_t)BATCH * H3 * 4;
    float* gh1 = (float*)w;           w += (size_t)BATCH * H3 * 4;
    float* gh2 = (float*)w;           w += (size_t)BATCH * H3 * 4;
    unsigned short* h_bf = (unsigned short*)w;   w += (size_t)BATCH * H3 * 2;
    unsigned short* comb_bf = (unsigned short*)w; w += (size_t)BATCH * D_IN * 2;
    unsigned short* hpW_bf = (unsigned short*)w;  w += (size_t)H3 * D_IN * 2;
    unsigned short* Whh_bf = (unsigned short*)w;  w += (size_t)3 * H3 * H * 2;
    unsigned short* Wihr_bf = (unsigned short*)w; w += (size_t)2 * H3 * H * 2;
    unsigned short* W1T_bf = (unsigned short*)w;  w += (size_t)T_STEPS * H * H * 2;

    // prologue
    k_comb<<<dim3((BATCH * D_IN) / 256), dim3(256), 0, stream>>>(z, cond, comb_bf, pos);
    k_conv<<<dim3((H3 * D_IN) / 2048), dim3(256), 0, stream>>>(hp_W, hpW_bf);
    k_conv<<<dim3((3 * H3 * H) / 2048), dim3(256), 0, stream>>>(W_hh, Whh_bf);
    k_conv<<<dim3((2 * H3 * H) / 2048), dim3(256), 0, stream>>>(W_ihr, Wihr_bf);
    k_trw1<<<dim3(16, 16, T_STEPS), dim3(256), 0, stream>>>(W1, W1T_bf);
    k_init<<<dim3(192), dim3(256), 0, stream>>>(comb_bf, hpW_bf, h, h_bf, hp_b);
    k_gh3<<<dim3(576), dim3(256), 0, stream>>>(h_bf, Whh_bf, gh0, gh1, gh2);

    for (int t = 0; t < T_STEPS; ++t) {
        int last = (t == T_STEPS - 1) ? 1 : 0;
        k_ew0<<<dim3(1024), dim3(256), 0, stream>>>(gh0, h, h_bf, W_ih0, b_ih, b_hh,
                                                    pos, partials, b2, out, t);
        k_dual<<<dim3(384), dim3(256), 0, stream>>>(h_bf, Wihr_bf, gi, Whh_bf, gh0,
                                                    last);
        k_ewl<<<dim3(1024), dim3(256), 0, stream>>>(gi, gh1, h, h_bf, b_ih + H3,
                                                    b_hh + H3, H);
        k_dual<<<dim3(384), dim3(256), 0, stream>>>(
            h_bf + H, Wihr_bf + (size_t)H3 * H, gi, Whh_bf + (size_t)H3 * H, gh1,
            last);
        k_ewl<<<dim3(1024), dim3(256), 0, stream>>>(gi, gh2, h, h_bf, b_ih + 2 * H3,
                                                    b_hh + 2 * H3, 2 * H);
        k_mlp_gh<<<dim3(256), dim3(256), 0, stream>>>(
            h_bf + 2 * H, W1T_bf + (size_t)t * H * H, b1 + (size_t)t * H,
            W2 + (size_t)t * H * 2, partials, Whh_bf + (size_t)2 * H3 * H, gh2,
            last);
    }
    k_posfin<<<dim3(8), dim3(256), 0, stream>>>(partials, pos, b2, out);
}